// Round 8
// baseline (224.574 us; speedup 1.0000x reference)
//
#include <hip/hip_runtime.h>
#include <cstdint>
#include <cstddef>

// ---------------------------------------------------------------------------
// InfiniAttention (fp32 I/O), 4 dispatches:
//   conv_all   : fp32->bf16 for x/W*/mem, + 0.5*mem^T
//   gemm_qkvl  : fused QKV projections + memory logits (XCD-grouped grid)
//   flash_attn : v15 — 32x32x16 MFMA flash, in-register softmax/P, KV-split
//                wave pairs with 64-KEY tiles (v13 fragment geometry),
//                single-buffer 2-barrier LDS, in-LDS exact combine
//   gemm_out64 : output projection, 64x128 tiles (XCD-grouped grid), fp32 out
// ---------------------------------------------------------------------------

typedef __bf16 bf16;
typedef bf16  bf16x8 __attribute__((ext_vector_type(8)));
typedef bf16  bf16x4 __attribute__((ext_vector_type(4)));
typedef float f32x4  __attribute__((ext_vector_type(4)));
typedef float f32x16 __attribute__((ext_vector_type(16)));
typedef int   i32x4  __attribute__((ext_vector_type(4)));
typedef int   i32x2  __attribute__((ext_vector_type(2)));

#define B_DIM 2
#define S_DIM 2048
#define E_DIM 1024
#define H_DIM 16
#define D_DIM 64
#define M_DIM 256
#define NROW  (B_DIM * S_DIM)          // 4096
// SCALE * log2(e) — softmax computed in exp2 domain
#define C1 0.18033688011112042f

#define MFMA32(a, b, c) __builtin_amdgcn_mfma_f32_32x32x16_bf16((a), (b), (c), 0, 0, 0)

__device__ __forceinline__ f32x16 zero16()
{
    f32x16 z;
#pragma unroll
    for (int i = 0; i < 16; ++i) z[i] = 0.f;
    return z;
}

// async global->LDS, 16B per lane; LDS dest is wave-uniform base
__device__ __forceinline__ void async_cp16(const bf16* g, bf16* l)
{
    __builtin_amdgcn_global_load_lds(
        (const __attribute__((address_space(1))) void*)g,
        (__attribute__((address_space(3))) void*)l, 16, 0, 0);
}

// ---------------------------------------------------------------------------
// Batched fp32 -> bf16: [x | Wq | Wk | Wv | Wo | mem] one dispatch; the mem
// branch also writes 0.5*mem^T (pre-folds the 0.5 combine factor).
// ---------------------------------------------------------------------------
__global__ void __launch_bounds__(256)
conv_all(const float* __restrict__ x,  const float* __restrict__ Wq,
         const float* __restrict__ Wk, const float* __restrict__ Wv,
         const float* __restrict__ Wo, const float* __restrict__ mem,
         bf16* __restrict__ xb,  bf16* __restrict__ Wqb,
         bf16* __restrict__ Wkb, bf16* __restrict__ Wvb,
         bf16* __restrict__ Wob, bf16* __restrict__ memb,
         bf16* __restrict__ memt)
{
    int t = blockIdx.x * 256 + threadIdx.x;
    const float* src; bf16* dst; int off; bool is_mem = false;
    if      (t <  524288) { src = x;   dst = xb;   off = t; }
    else if (t <  655360) { src = Wq;  dst = Wqb;  off = t - 524288; }
    else if (t <  786432) { src = Wk;  dst = Wkb;  off = t - 655360; }
    else if (t <  917504) { src = Wv;  dst = Wvb;  off = t - 786432; }
    else if (t < 1048576) { src = Wo;  dst = Wob;  off = t - 917504; }
    else                  { src = mem; dst = memb; off = t - 1048576; is_mem = true; }
    const float4* p = (const float4*)src + (size_t)off * 2;
    float4 a = p[0], b = p[1];
    bf16x8 o;
    o[0] = (bf16)a.x; o[1] = (bf16)a.y; o[2] = (bf16)a.z; o[3] = (bf16)a.w;
    o[4] = (bf16)b.x; o[5] = (bf16)b.y; o[6] = (bf16)b.z; o[7] = (bf16)b.w;
    *(bf16x8*)(dst + (size_t)off * 8) = o;
    if (is_mem) {
        int r = off >> 7, c0 = (off & 127) * 8;   // mem is [256 x 1024]
        float h[8] = {a.x, a.y, a.z, a.w, b.x, b.y, b.z, b.w};
#pragma unroll
        for (int j = 0; j < 8; ++j)
            memt[(size_t)(c0 + j) * M_DIM + r] = (bf16)(0.5f * h[j]);
    }
}

// ---------------------------------------------------------------------------
// NT GEMM core: 128x128 tile, BK=32, 4 waves, global_load_lds staging with
// XOR chunk swizzle on the GLOBAL address, LDS double-buffer, one barrier
// per K-step.
// ---------------------------------------------------------------------------
struct GemmAcc { f32x4 a[4][4]; };

__device__ __forceinline__ void
gemm_core(const bf16* __restrict__ A, const bf16* __restrict__ Bm,
          int K, int m0, int n0, bf16* As, bf16* Bs, GemmAcc& R)
{
    const int tid  = threadIdx.x;
    const int lane = tid & 63;
    const int wave = tid >> 6;
    const int quad = lane >> 4;
    const int l16  = lane & 15;
    const int wm   = (wave >> 1) * 64;
    const int wn   = (wave & 1) * 64;

#pragma unroll
    for (int i = 0; i < 4; ++i)
#pragma unroll
        for (int j = 0; j < 4; ++j)
            R.a[i][j] = f32x4{0.f, 0.f, 0.f, 0.f};

    int s_c0  = wave * 128 + lane;
    int s_r0  = s_c0 >> 2;
    int s_k0  = (s_c0 & 3) ^ ((s_r0 >> 1) & 3);
    int s_c1  = s_c0 + 64;
    int s_r1  = s_c1 >> 2;
    int s_k1  = (s_c1 & 3) ^ ((s_r1 >> 1) & 3);
    const bf16* gA0 = A  + (size_t)(m0 + s_r0) * K + s_k0 * 8;
    const bf16* gA1 = A  + (size_t)(m0 + s_r1) * K + s_k1 * 8;
    const bf16* gB0 = Bm + (size_t)(n0 + s_r0) * K + s_k0 * 8;
    const bf16* gB1 = Bm + (size_t)(n0 + s_r1) * K + s_k1 * 8;

#define STAGE(buf, k0)                                                     \
    do {                                                                   \
        async_cp16(gA0 + (k0), &As[(buf) * 4096 + wave * 1024]);           \
        async_cp16(gA1 + (k0), &As[(buf) * 4096 + wave * 1024 + 512]);     \
        async_cp16(gB0 + (k0), &Bs[(buf) * 4096 + wave * 1024]);           \
        async_cp16(gB1 + (k0), &Bs[(buf) * 4096 + wave * 1024 + 512]);     \
    } while (0)

    STAGE(0, 0);
    int buf = 0;
    for (int k0 = 0; k0 < K; k0 += 32) {
        __syncthreads();
        if (k0 + 32 < K) STAGE(buf ^ 1, k0 + 32);

        const bf16* Ab = As + buf * 4096;
        const bf16* Bb = Bs + buf * 4096;
        bf16x8 af[4], bfr[4];
#pragma unroll
        for (int mi = 0; mi < 4; ++mi) {
            int m    = wm + mi * 16 + l16;
            int slot = quad ^ ((m >> 1) & 3);
            af[mi]   = *(const bf16x8*)(&Ab[(m * 4 + slot) * 8]);
        }
#pragma unroll
        for (int ni = 0; ni < 4; ++ni) {
            int n    = wn + ni * 16 + l16;
            int slot = quad ^ ((n >> 1) & 3);
            bfr[ni]  = *(const bf16x8*)(&Bb[(n * 4 + slot) * 8]);
        }
#pragma unroll
        for (int mi = 0; mi < 4; ++mi)
#pragma unroll
            for (int ni = 0; ni < 4; ++ni)
                R.a[mi][ni] = __builtin_amdgcn_mfma_f32_16x16x32_bf16(
                    af[mi], bfr[ni], R.a[mi][ni], 0, 0, 0);
        buf ^= 1;
    }
#undef STAGE
}

// ---------------------------------------------------------------------------
// Fused QKV + memory-logits, XCD-grouped 1D grid (832 blocks).
// C/D layout: col = lane&15, row = quad*4 + r   [m89-verified]
// ---------------------------------------------------------------------------
__global__ void __launch_bounds__(256, 3)
gemm_qkvl(const bf16* __restrict__ A,
          const bf16* __restrict__ Wq, const bf16* __restrict__ Wk,
          const bf16* __restrict__ Wv, const bf16* __restrict__ memb,
          const float* __restrict__ bq, const float* __restrict__ bk,
          const float* __restrict__ bv,
          bf16* __restrict__ q, bf16* __restrict__ k,
          bf16* __restrict__ vt, bf16* __restrict__ lg)
{
    __shared__ __align__(16) bf16 As[2 * 4096];
    __shared__ __align__(16) bf16 Bs[2 * 4096];
    const int lid  = blockIdx.x;
    const int xcd  = lid & 7;
    const int idx  = lid >> 3;            // 0..103
    const int mloc = idx / 26;            // 0..3
    const int nn   = idx - mloc * 26;     // 0..25
    const int m0   = (mloc * 8 + xcd) * 128;
    const int widx = (nn < 24) ? (nn >> 3) : 3;
    const int n0   = (nn < 24) ? (nn & 7) * 128 : (nn - 24) * 128;
    const bf16*  Bm = (widx == 0) ? Wq : (widx == 1) ? Wk :
                      (widx == 2) ? Wv : memb;
    GemmAcc R;
    gemm_core(A, Bm, E_DIM, m0, n0, As, Bs, R);

    const int lane = threadIdx.x & 63, wave = threadIdx.x >> 6;
    const int quad = lane >> 4, l16 = lane & 15;
    const int wm = (wave >> 1) * 64, wn = (wave & 1) * 64;

    if (widx == 0 || widx == 1) {
        bf16* C = (widx == 0) ? q : k;
        const float* bi = (widx == 0) ? bq : bk;
        float scale = (widx == 0) ? C1 : 1.0f;
#pragma unroll
        for (int ni = 0; ni < 4; ++ni) {
            int col  = n0 + wn + ni * 16 + l16;
            float bb = bi[col];
#pragma unroll
            for (int mi = 0; mi < 4; ++mi)
#pragma unroll
                for (int r = 0; r < 4; ++r) {
                    int rowg = m0 + wm + mi * 16 + quad * 4 + r;
                    C[(size_t)rowg * E_DIM + col] =
                        (bf16)((R.a[mi][ni][r] + bb) * scale);
                }
        }
    } else if (widx == 2) {
#pragma unroll
        for (int ni = 0; ni < 4; ++ni) {
            int col = n0 + wn + ni * 16 + l16;   // h*64 + d
            float bb = bv[col];
#pragma unroll
            for (int mi = 0; mi < 4; ++mi) {
                int row0 = m0 + wm + mi * 16 + quad * 4;  // b*2048 + s
                int bidx = row0 >> 11, s = row0 & 2047;
                bf16x4 pk;
#pragma unroll
                for (int r = 0; r < 4; ++r) pk[r] = (bf16)(R.a[mi][ni][r] + bb);
                *(bf16x4*)(&vt[((size_t)(bidx * H_DIM) * 64 + col) * S_DIM + s]) = pk;
            }
        }
    } else {
#pragma unroll
        for (int ni = 0; ni < 4; ++ni) {
            int col = n0 + wn + ni * 16 + l16;
#pragma unroll
            for (int mi = 0; mi < 4; ++mi)
#pragma unroll
                for (int r = 0; r < 4; ++r) {
                    int rowg = m0 + wm + mi * 16 + quad * 4 + r;
                    lg[(size_t)rowg * M_DIM + col] = (bf16)R.a[mi][ni][r];
                }
        }
    }
}

// ---------------------------------------------------------------------------
// Output projection: 64x128 tiles, XCD-grouped 1D grid (512 blocks).
// ---------------------------------------------------------------------------
__global__ void __launch_bounds__(256, 2)
gemm_out64(const bf16* __restrict__ A, const bf16* __restrict__ Bm,
           const float* __restrict__ bias, float* __restrict__ C)
{
    __shared__ __align__(16) bf16 As[2 * 2048];   //  8 KB (64x32 dbuf)
    __shared__ __align__(16) bf16 Bs[2 * 4096];   // 16 KB (128x32 dbuf)
    const int tid  = threadIdx.x;
    const int lane = tid & 63;
    const int wave = tid >> 6;
    const int quad = lane >> 4;
    const int l16  = lane & 15;
    const int wm   = (wave >> 1) * 32;
    const int wn   = (wave & 1) * 64;
    const int lid  = blockIdx.x;
    const int xcd  = lid & 7;
    const int idx  = lid >> 3;        // 0..63
    const int mloc = idx >> 3;        // 0..7
    const int nn   = idx & 7;
    const int m0   = (mloc * 8 + xcd) * 64;
    const int n0   = nn * 128;
    const int K    = E_DIM;

    f32x4 acc[2][4];
#pragma unroll
    for (int i = 0; i < 2; ++i)
#pragma unroll
        for (int j = 0; j < 4; ++j) acc[i][j] = f32x4{0.f, 0.f, 0.f, 0.f};

    int a_s  = wave * 64 + lane;
    int a_r  = a_s >> 2;
    int a_k  = (a_s & 3) ^ ((a_r >> 1) & 3);
    int b_s0 = wave * 128 + lane;
    int b_r0 = b_s0 >> 2;
    int b_k0 = (b_s0 & 3) ^ ((b_r0 >> 1) & 3);
    int b_s1 = b_s0 + 64;
    int b_r1 = b_s1 >> 2;
    int b_k1 = (b_s1 & 3) ^ ((b_r1 >> 1) & 3);
    const bf16* gA  = A  + (size_t)(m0 + a_r) * K + a_k * 8;
    const bf16* gB0 = Bm + (size_t)(n0 + b_r0) * K + b_k0 * 8;
    const bf16* gB1 = Bm + (size_t)(n0 + b_r1) * K + b_k1 * 8;

#define STAGE64(buf, k0)                                                   \
    do {                                                                   \
        async_cp16(gA  + (k0), &As[(buf) * 2048 + wave * 512]);            \
        async_cp16(gB0 + (k0), &Bs[(buf) * 4096 + wave * 1024]);           \
        async_cp16(gB1 + (k0), &Bs[(buf) * 4096 + wave * 1024 + 512]);     \
    } while (0)

    STAGE64(0, 0);
    int buf = 0;
    for (int k0 = 0; k0 < K; k0 += 32) {
        __syncthreads();
        if (k0 + 32 < K) STAGE64(buf ^ 1, k0 + 32);
        const bf16* Ab = As + buf * 2048;
        const bf16* Bb = Bs + buf * 4096;
        bf16x8 af[2], bfr[4];
#pragma unroll
        for (int mi = 0; mi < 2; ++mi) {
            int m    = wm + mi * 16 + l16;
            int slot = quad ^ ((m >> 1) & 3);
            af[mi]   = *(const bf16x8*)(&Ab[(m * 4 + slot) * 8]);
        }
#pragma unroll
        for (int ni = 0; ni < 4; ++ni) {
            int n    = wn + ni * 16 + l16;
            int slot = quad ^ ((n >> 1) & 3);
            bfr[ni]  = *(const bf16x8*)(&Bb[(n * 4 + slot) * 8]);
        }
#pragma unroll
        for (int mi = 0; mi < 2; ++mi)
#pragma unroll
            for (int ni = 0; ni < 4; ++ni)
                acc[mi][ni] = __builtin_amdgcn_mfma_f32_16x16x32_bf16(
                    af[mi], bfr[ni], acc[mi][ni], 0, 0, 0);
        buf ^= 1;
    }
#undef STAGE64

#pragma unroll
    for (int ni = 0; ni < 4; ++ni) {
        int col  = n0 + wn + ni * 16 + l16;
        float bb = bias[col];
#pragma unroll
        for (int mi = 0; mi < 2; ++mi)
#pragma unroll
            for (int r = 0; r < 4; ++r) {
                int rowg = m0 + wm + mi * 16 + quad * 4 + r;
                C[(size_t)rowg * E_DIM + col] = acc[mi][ni][r] + bb;
            }
    }
}

// ---------------------------------------------------------------------------
// Flash attention v15 — KV-split pairs with v13's 64-KEY tile geometry.
//
// v13 (72us): best per-iter efficiency, but grid 512 => 2 blocks/CU, wave-
// starved.  v14 (77us): KV-split raised occupancy but shrank tiles to 32
// keys => 64B LDS rows => 8-way V bank conflicts (10.5M vs 4.2M) + halved
// per-iter MFMA work.  v15 keeps v13's EXACT fragment formulas / swizzles /
// pi fold (128B rows, ^(row&7)), and fits the pair-split in 32 KB by going
// SINGLE-buffered with 2 barriers/iter:
//   issue K loads | QK^T (LDS reads) | issue V loads | exp2->P in regs |
//   PV (LDS reads) | barrier A (reads done) | write next tile | barrier B
// Grid 1024, launch_bounds(256,3) -> 3 blocks/CU = 12 waves/CU (2x v13 TLP).
// Exact combine (plain exp2, no max): O = O0+O1, osum = osum0+osum1 via LDS.
// ---------------------------------------------------------------------------
__global__ void __launch_bounds__(256, 3)
flash_attn(const bf16* __restrict__ q, const bf16* __restrict__ k,
           const bf16* __restrict__ vt, const bf16* __restrict__ lg,
           const bf16* __restrict__ memt, bf16* __restrict__ outc)
{
    // 32 KB: pair p at SM + p*8192: [K 4096 | V 4096] (single-buffered)
    __shared__ __align__(16) bf16 SM[16384];
    const int tid  = threadIdx.x;
    const int lane = tid & 63;
    const int wave = tid >> 6;     // 0..3
    const int hi   = lane >> 5;
    const int l32  = lane & 31;
    const int pw   = wave & 1;     // row-half within block
    const int ks   = wave >> 1;    // KV half (pair id)

    // XCD-swizzled decode: 32 q-tiles (64 rows) of one (b,h); 4 bh per XCD
    const int lid = blockIdx.x;               // 0..1023
    const int xcd = lid & 7;
    const int kk  = lid >> 3;                 // 0..127
    const int qt  = kk & 31;                  // 0..31
    const int p   = ((kk >> 5) << 3) | xcd;   // 0..31
    const int b   = p >> 4;
    const int h   = p & 15;
    const int qw  = qt * 64 + pw * 32;        // this wave's first q row

    const bf16* qb = q  + (size_t)(b * S_DIM + qw) * E_DIM + h * D_DIM;
    const bf16* kb = k  + (size_t)(b * S_DIM) * E_DIM + h * D_DIM;
    const bf16* vb = vt + (size_t)(b * H_DIM + h) * D_DIM * S_DIM;
    const int   kv0 = ks * 1024;              // pair's key range start

    bf16* Kp = SM + ks * 8192;                // [64 key][64 d], chunk-swz
    bf16* Vp = SM + ks * 8192 + 4096;         // [64 d][64 key], pi+chunk-swz

    // staging: pair lane pl 0..127, 4 slots pl+128*i; slot s -> row s>>3,
    // global chunk gc = (s&7)^(row&7)  (row+16 preserves both)
    const int pl  = pw * 64 + lane;
    const int r0  = pl >> 3;                  // 0..15
    const int g0  = (pl & 7) ^ (r0 & 7);
    const bf16* gK = kb + (size_t)(kv0 + r0) * E_DIM + g0 * 8;
    const bf16* gV = vb + (size_t)r0 * S_DIM + kv0 + g0 * 8;
    const int kd  = pl * 8;                   // K LDS dest (linear, +1024*i)
    // V pi fold (v13 formula): 16B global chunk g0 -> two b64 at chunks
    // ((g0&~1)|{0,1})^(r0&7), in-chunk elem offset (g0&1)*4
    const int va  = r0 * 64 + (((g0 & ~1)    ) ^ (r0 & 7)) * 8 + (g0 & 1) * 4;
    const int vb2 = r0 * 64 + (((g0 & ~1) | 1) ^ (r0 & 7)) * 8 + (g0 & 1) * 4;

    // Q B-frags (pre-scaled by C1): chunk c covers d = c*16 + hi*8 + j
    bf16x8 qfr[4];
#pragma unroll
    for (int c = 0; c < 4; ++c)
        qfr[c] = *(const bf16x8*)(qb + (size_t)l32 * E_DIM + c * 16 + hi * 8);

    bf16x8 vones;
#pragma unroll
    for (int j = 0; j < 8; ++j) vones[j] = (bf16)1.0f;

    f32x16 o0 = zero16(), o1 = zero16(), osum = zero16();

    // ---- prologue: reg-load tile 0 (keys kv0..kv0+63), write, barrier ----
    {
        i32x4 rk[4], rv[4];
#pragma unroll
        for (int i = 0; i < 4; ++i) rk[i] = *(const i32x4*)(gK + (size_t)(16 * i) * E_DIM);
#pragma unroll
        for (int i = 0; i < 4; ++i) rv[i] = *(const i32x4*)(gV + (size_t)(16 * i) * S_DIM);
#pragma unroll
        for (int i = 0; i < 4; ++i) *(i32x4*)(Kp + kd + i * 1024) = rk[i];
#pragma unroll
        for (int i = 0; i < 4; ++i) {
            *(i32x2*)(Vp + va  + i * 1024) = i32x2{rv[i][0], rv[i][1]};
            *(i32x2*)(Vp + vb2 + i * 1024) = i32x2{rv[i][2], rv[i][3]};
        }
    }
    __syncthreads();

    for (int kt = 0; kt < 1024; kt += 64) {
        const bool pre = (kt + 64 < 1024);
        i32x4 nk[4], nv[4];
        if (pre) {
            const size_t ko = (size_t)(kt + 64) * E_DIM;
#pragma unroll
            for (int i = 0; i < 4; ++i)
                nk[i] = *(const i32x4*)(gK + ko + (size_t)(16 * i) * E_DIM);
        }

        // ---- QK^T: S^T[key][q], two 32-key halves, d in 4 chunks of 16 ---
        f32x16 sc0 = zero16(), sc1 = zero16();
        __builtin_amdgcn_s_setprio(1);
#pragma unroll
        for (int c = 0; c < 4; ++c) {
            const int swz = ((c * 2 + hi) ^ (l32 & 7)) * 8;
            bf16x8 kf0 = *(const bf16x8*)(&Kp[l32 * 64 + swz]);
            bf16x8 kf1 = *(const bf16x8*)(&Kp[(32 + l32) * 64 + swz]);
            sc0 = MFMA32(kf0, qfr[c], sc0);
            sc1 = MFMA32(kf1, qfr[c], sc1);
        }
        __builtin_amdgcn_s_setprio(0);

        if (pre) {
#pragma unroll
            for (int i = 0; i < 4; ++i)
                nv[i] = *(const i32x4*)(gV + (kt + 64) + (size_t)(16 * i) * S_DIM);
        }

        // ---- in-register P (pi-permuted): ap[kc][j]=exp2(sc[kc>>1][..]) --
        bf16x8 ap[4];
#pragma unroll
        for (int kc = 0; kc < 4; ++kc) {
            const f32x16 sct = (kc < 2) ? sc0 : sc1;
            const int base = (kc & 1) * 8;
#pragma unroll
            for (int j = 0; j < 8; ++j)
                ap[kc][j] = (bf16)exp2f(sct[base + j]);
        }

        // ---- O += P @ V_perm ;  osum += P @ 1 ----------------------------
        __builtin_amdgcn_s_setprio(1);
#pragma unroll
        for (int kc = 0; kc < 4; ++kc) {
            const int swz = ((kc * 2 + hi) ^ (l32 & 7)) * 8;
            bf16x8 vf0 = *(const bf16x8*)(&Vp[l32 * 64 + swz]);
            bf16x8 vf1 = *(const bf16x8*)(&Vp[(32 + l32) * 64 + swz]);
            o0   = MFMA32(ap[kc], vf0, o0);
            o1   = MFMA32(ap[kc], vf1, o1);
            osum = MFMA32(ap[kc], vones, osum);
        }
        __builtin_amdgcn_s_setprio(0);

        __syncthreads();                       // A: all reads of tile done
        if (pre) {
#pragma unroll
            for (int i = 0; i < 4; ++i) *(i32x4*)(Kp + kd + i * 1024) = nk[i];
#pragma unroll
            for (int i = 0; i < 4; ++i) {
                *(i32x2*)(Vp + va  + i * 1024) = i32x2{nv[i][0], nv[i][1]};
                *(i32x2*)(Vp + vb2 + i * 1024) = i32x2{nv[i][2], nv[i][3]};
            }
        }
        __syncthreads();                       // B: next tile visible
    }

    // ---- KV-split combine via LDS (exact: plain exp2, no max) ------------
    float* smf = (float*)SM;
    if (ks == 1) {
        float* dst = smf + pw * 3072 + lane;
#pragma unroll
        for (int i = 0; i < 16; ++i) dst[i * 64]        = o0[i];
#pragma unroll
        for (int i = 0; i < 16; ++i) dst[(16 + i) * 64] = o1[i];
#pragma unroll
        for (int i = 0; i < 16; ++i) dst[(32 + i) * 64] = osum[i];
    }
    __syncthreads();
    if (ks == 1) return;
    {
        const float* src = smf + pw * 3072 + lane;
#pragma unroll
        for (int i = 0; i < 16; ++i) o0[i]   += src[i * 64];
#pragma unroll
        for (int i = 0; i < 16; ++i) o1[i]   += src[(16 + i) * 64];
#pragma unroll
        for (int i = 0; i < 16; ++i) osum[i] += src[(32 + i) * 64];
    }

    float linv[16];
#pragma unroll
    for (int r = 0; r < 16; ++r) linv[r] = 1.f / osum[r];

    // ---- fused memory cross-attn (32x32): ep = exp2(C1*lg),
    //      macc = ep @ (0.5*mem^T), msum = ep @ 1 --------------------------
    const bf16* Pr = lg   + (size_t)(b * S_DIM + qw) * M_DIM;
    const bf16* Mt = memt + (size_t)(h * D_DIM) * M_DIM;
    f32x16 macc0 = zero16(), macc1 = zero16(), msum = zero16();
#pragma unroll
    for (int mc = 0; mc < 16; ++mc) {
        bf16x8 raw = *(const bf16x8*)(Pr + (size_t)l32 * M_DIM + mc * 16 + hi * 8);
        bf16x8 epv;
#pragma unroll
        for (int j = 0; j < 8; ++j) epv[j] = (bf16)exp2f(C1 * (float)raw[j]);
        bf16x8 bm0 = *(const bf16x8*)(Mt + (size_t)l32 * M_DIM        + mc * 16 + hi * 8);
        bf16x8 bm1 = *(const bf16x8*)(Mt + (size_t)(32 + l32) * M_DIM + mc * 16 + hi * 8);
        macc0 = MFMA32(epv, bm0, macc0);
        macc1 = MFMA32(epv, bm1, macc1);
        msum  = MFMA32(epv, vones, msum);
    }

    // ---- epilogue: comb = attn/l + mem/msum ------------------------------
    bf16* ob = outc + (size_t)(b * S_DIM + qw) * E_DIM + h * D_DIM;
#pragma unroll
    for (int r = 0; r < 16; ++r) {
        const int qrow = (r & 3) + 8 * (r >> 2) + 4 * hi;
        const float mi = 1.f / msum[r];
        ob[(size_t)qrow * E_DIM + l32]      = (bf16)(o0[r] * linv[r] + macc0[r] * mi);
        ob[(size_t)qrow * E_DIM + 32 + l32] = (bf16)(o1[r] * linv[r] + macc1[r] * mi);
    }
}

// ---------------------------------------------------------------------------
extern "C" void kernel_launch(void* const* d_in, const int* in_sizes, int n_in,
                              void* d_out, int out_size, void* d_ws, size_t ws_size,
                              hipStream_t stream)
{
    (void)in_sizes; (void)n_in; (void)out_size; (void)ws_size;
    const float* x   = (const float*)d_in[0];
    const float* Wq  = (const float*)d_in[1];
    const float* bq  = (const float*)d_in[2];
    const float* Wk  = (const float*)d_in[3];
    const float* bk  = (const float*)d_in[4];
    const float* Wv  = (const float*)d_in[5];
    const float* bv  = (const float*)d_in[6];
    const float* Wo  = (const float*)d_in[7];
    const float* bo  = (const float*)d_in[8];
    const float* mem = (const float*)d_in[9];
    float* out = (float*)d_out;

    // bf16 workspace layout (elements), ~34 MB
    bf16* w = (bf16*)d_ws;
    const size_t NE = (size_t)NROW * E_DIM;            // 4 Mi
    const size_t EE = (size_t)E_DIM * E_DIM;           // 1 Mi
    bf16* xb      = w;                                 // 4M
    bf16* q_ws    = w + NE;                            // 4M (later: comb)
    bf16* k_ws    = w + 2 * NE;                        // 4M
    bf16* Wqb     = w + 3 * NE;                        // 1M
    bf16* Wkb     = Wqb + EE;
    bf16* Wvb     = Wkb + EE;
    bf16* Wob     = Wvb + EE;
    bf16* memb    = Wob + EE;                          // 0.25M
    bf16* lg_ws   = memb + (size_t)M_DIM * E_DIM;      // 1M (raw logits)
    bf16* memt_ws = lg_ws + (size_t)NROW * M_DIM;      // 0.25M
    // v^T lives inside d_out (4M bf16 in 16MB fp32 buffer), consumed by
    // flash before the final GEMM overwrites d_out.
    bf16* vt_ws = (bf16*)d_out;                        // 4M

    dim3 blk(256);

    // ---- batched fp32 -> bf16 (+ 0.5*mem^T) -------------------------------
    conv_all<<<dim3(4224), blk, 0, stream>>>(
        x, Wq, Wk, Wv, Wo, mem, xb, Wqb, Wkb, Wvb, Wob, memb, memt_ws);

    // ---- fused QKV + raw memory logits (832 blocks, XCD-grouped) ----------
    gemm_qkvl<<<dim3(832), blk, 0, stream>>>(
        xb, Wqb, Wkb, Wvb, memb, bq, bk, bv, q_ws, k_ws, vt_ws, lg_ws);

    // ---- flash attention + fused memory cross-attn (1024 blocks) ----------
    flash_attn<<<dim3(1024), blk, 0, stream>>>(
        q_ws, k_ws, vt_ws, lg_ws, memt_ws, q_ws);

    // ---- output projection (512 blocks, XCD-grouped, fp32 out) ------------
    gemm_out64<<<dim3(512), blk, 0, stream>>>(
        q_ws, Wob, bo, out);
}

// Round 9
// 213.785 us; speedup vs baseline: 1.0505x; 1.0505x over previous
//
#include <hip/hip_runtime.h>
#include <cstdint>
#include <cstddef>

// ---------------------------------------------------------------------------
// InfiniAttention (fp32 I/O), 4 dispatches:
//   conv_all   : fp32->bf16 for x/W*/mem, + 0.5*mem^T  (grid-stride, 2048 blk)
//   gemm_qkvl  : fused QKV projections + memory logits (XCD-grouped grid)
//   flash_attn : v13 (PROVEN 72us) — 32x32x16 MFMA flash, fully in-register
//                softmax/P (pi = bitswap(2,3) key permutation folded into V
//                staging), reg-staged dbuf LDS, fused mem cross-attn epilogue
//   gemm_out64 : output projection, 64x128 tiles (XCD-grouped grid), fp32 out
// v14 (KV-split 32-key tiles) and v15 (single-buf 2-barrier) both regressed;
// v13 is the structural optimum for this flash family.
// ---------------------------------------------------------------------------

typedef __bf16 bf16;
typedef bf16  bf16x8 __attribute__((ext_vector_type(8)));
typedef bf16  bf16x4 __attribute__((ext_vector_type(4)));
typedef float f32x4  __attribute__((ext_vector_type(4)));
typedef float f32x16 __attribute__((ext_vector_type(16)));
typedef int   i32x4  __attribute__((ext_vector_type(4)));
typedef int   i32x2  __attribute__((ext_vector_type(2)));

#define B_DIM 2
#define S_DIM 2048
#define E_DIM 1024
#define H_DIM 16
#define D_DIM 64
#define M_DIM 256
#define NROW  (B_DIM * S_DIM)          // 4096
// SCALE * log2(e) — softmax computed in exp2 domain
#define C1 0.18033688011112042f

#define MFMA32(a, b, c) __builtin_amdgcn_mfma_f32_32x32x16_bf16((a), (b), (c), 0, 0, 0)

__device__ __forceinline__ f32x16 zero16()
{
    f32x16 z;
#pragma unroll
    for (int i = 0; i < 16; ++i) z[i] = 0.f;
    return z;
}

// async global->LDS, 16B per lane; LDS dest is wave-uniform base
__device__ __forceinline__ void async_cp16(const bf16* g, bf16* l)
{
    __builtin_amdgcn_global_load_lds(
        (const __attribute__((address_space(1))) void*)g,
        (__attribute__((address_space(3))) void*)l, 16, 0, 0);
}

// ---------------------------------------------------------------------------
// Batched fp32 -> bf16: [x | Wq | Wk | Wv | Wo | mem] one dispatch; the mem
// branch also writes 0.5*mem^T.  Grid-stride at 2048 blocks (G11).
// ---------------------------------------------------------------------------
__global__ void __launch_bounds__(256)
conv_all(const float* __restrict__ x,  const float* __restrict__ Wq,
         const float* __restrict__ Wk, const float* __restrict__ Wv,
         const float* __restrict__ Wo, const float* __restrict__ mem,
         bf16* __restrict__ xb,  bf16* __restrict__ Wqb,
         bf16* __restrict__ Wkb, bf16* __restrict__ Wvb,
         bf16* __restrict__ Wob, bf16* __restrict__ memb,
         bf16* __restrict__ memt)
{
    for (int t = blockIdx.x * 256 + threadIdx.x; t < 1081344; t += 2048 * 256) {
        const float* src; bf16* dst; int off; bool is_mem = false;
        if      (t <  524288) { src = x;   dst = xb;   off = t; }
        else if (t <  655360) { src = Wq;  dst = Wqb;  off = t - 524288; }
        else if (t <  786432) { src = Wk;  dst = Wkb;  off = t - 655360; }
        else if (t <  917504) { src = Wv;  dst = Wvb;  off = t - 786432; }
        else if (t < 1048576) { src = Wo;  dst = Wob;  off = t - 917504; }
        else                  { src = mem; dst = memb; off = t - 1048576; is_mem = true; }
        const float4* p = (const float4*)src + (size_t)off * 2;
        float4 a = p[0], b = p[1];
        bf16x8 o;
        o[0] = (bf16)a.x; o[1] = (bf16)a.y; o[2] = (bf16)a.z; o[3] = (bf16)a.w;
        o[4] = (bf16)b.x; o[5] = (bf16)b.y; o[6] = (bf16)b.z; o[7] = (bf16)b.w;
        *(bf16x8*)(dst + (size_t)off * 8) = o;
        if (is_mem) {
            int r = off >> 7, c0 = (off & 127) * 8;   // mem is [256 x 1024]
            float h[8] = {a.x, a.y, a.z, a.w, b.x, b.y, b.z, b.w};
#pragma unroll
            for (int j = 0; j < 8; ++j)
                memt[(size_t)(c0 + j) * M_DIM + r] = (bf16)(0.5f * h[j]);
        }
    }
}

// ---------------------------------------------------------------------------
// NT GEMM core: 128x128 tile, BK=32, 4 waves, global_load_lds staging with
// XOR chunk swizzle on the GLOBAL address, LDS double-buffer, one barrier
// per K-step.
// ---------------------------------------------------------------------------
struct GemmAcc { f32x4 a[4][4]; };

__device__ __forceinline__ void
gemm_core(const bf16* __restrict__ A, const bf16* __restrict__ Bm,
          int K, int m0, int n0, bf16* As, bf16* Bs, GemmAcc& R)
{
    const int tid  = threadIdx.x;
    const int lane = tid & 63;
    const int wave = tid >> 6;
    const int quad = lane >> 4;
    const int l16  = lane & 15;
    const int wm   = (wave >> 1) * 64;
    const int wn   = (wave & 1) * 64;

#pragma unroll
    for (int i = 0; i < 4; ++i)
#pragma unroll
        for (int j = 0; j < 4; ++j)
            R.a[i][j] = f32x4{0.f, 0.f, 0.f, 0.f};

    int s_c0  = wave * 128 + lane;
    int s_r0  = s_c0 >> 2;
    int s_k0  = (s_c0 & 3) ^ ((s_r0 >> 1) & 3);
    int s_c1  = s_c0 + 64;
    int s_r1  = s_c1 >> 2;
    int s_k1  = (s_c1 & 3) ^ ((s_r1 >> 1) & 3);
    const bf16* gA0 = A  + (size_t)(m0 + s_r0) * K + s_k0 * 8;
    const bf16* gA1 = A  + (size_t)(m0 + s_r1) * K + s_k1 * 8;
    const bf16* gB0 = Bm + (size_t)(n0 + s_r0) * K + s_k0 * 8;
    const bf16* gB1 = Bm + (size_t)(n0 + s_r1) * K + s_k1 * 8;

#define STAGE(buf, k0)                                                     \
    do {                                                                   \
        async_cp16(gA0 + (k0), &As[(buf) * 4096 + wave * 1024]);           \
        async_cp16(gA1 + (k0), &As[(buf) * 4096 + wave * 1024 + 512]);     \
        async_cp16(gB0 + (k0), &Bs[(buf) * 4096 + wave * 1024]);           \
        async_cp16(gB1 + (k0), &Bs[(buf) * 4096 + wave * 1024 + 512]);     \
    } while (0)

    STAGE(0, 0);
    int buf = 0;
    for (int k0 = 0; k0 < K; k0 += 32) {
        __syncthreads();
        if (k0 + 32 < K) STAGE(buf ^ 1, k0 + 32);

        const bf16* Ab = As + buf * 4096;
        const bf16* Bb = Bs + buf * 4096;
        bf16x8 af[4], bfr[4];
#pragma unroll
        for (int mi = 0; mi < 4; ++mi) {
            int m    = wm + mi * 16 + l16;
            int slot = quad ^ ((m >> 1) & 3);
            af[mi]   = *(const bf16x8*)(&Ab[(m * 4 + slot) * 8]);
        }
#pragma unroll
        for (int ni = 0; ni < 4; ++ni) {
            int n    = wn + ni * 16 + l16;
            int slot = quad ^ ((n >> 1) & 3);
            bfr[ni]  = *(const bf16x8*)(&Bb[(n * 4 + slot) * 8]);
        }
#pragma unroll
        for (int mi = 0; mi < 4; ++mi)
#pragma unroll
            for (int ni = 0; ni < 4; ++ni)
                R.a[mi][ni] = __builtin_amdgcn_mfma_f32_16x16x32_bf16(
                    af[mi], bfr[ni], R.a[mi][ni], 0, 0, 0);
        buf ^= 1;
    }
#undef STAGE
}

// ---------------------------------------------------------------------------
// Fused QKV + memory-logits, XCD-grouped 1D grid (832 blocks).
// C/D layout: col = lane&15, row = quad*4 + r   [m89-verified]
// ---------------------------------------------------------------------------
__global__ void __launch_bounds__(256, 3)
gemm_qkvl(const bf16* __restrict__ A,
          const bf16* __restrict__ Wq, const bf16* __restrict__ Wk,
          const bf16* __restrict__ Wv, const bf16* __restrict__ memb,
          const float* __restrict__ bq, const float* __restrict__ bk,
          const float* __restrict__ bv,
          bf16* __restrict__ q, bf16* __restrict__ k,
          bf16* __restrict__ vt, bf16* __restrict__ lg)
{
    __shared__ __align__(16) bf16 As[2 * 4096];
    __shared__ __align__(16) bf16 Bs[2 * 4096];
    const int lid  = blockIdx.x;
    const int xcd  = lid & 7;
    const int idx  = lid >> 3;            // 0..103
    const int mloc = idx / 26;            // 0..3
    const int nn   = idx - mloc * 26;     // 0..25
    const int m0   = (mloc * 8 + xcd) * 128;
    const int widx = (nn < 24) ? (nn >> 3) : 3;
    const int n0   = (nn < 24) ? (nn & 7) * 128 : (nn - 24) * 128;
    const bf16*  Bm = (widx == 0) ? Wq : (widx == 1) ? Wk :
                      (widx == 2) ? Wv : memb;
    GemmAcc R;
    gemm_core(A, Bm, E_DIM, m0, n0, As, Bs, R);

    const int lane = threadIdx.x & 63, wave = threadIdx.x >> 6;
    const int quad = lane >> 4, l16 = lane & 15;
    const int wm = (wave >> 1) * 64, wn = (wave & 1) * 64;

    if (widx == 0 || widx == 1) {
        bf16* C = (widx == 0) ? q : k;
        const float* bi = (widx == 0) ? bq : bk;
        float scale = (widx == 0) ? C1 : 1.0f;
#pragma unroll
        for (int ni = 0; ni < 4; ++ni) {
            int col  = n0 + wn + ni * 16 + l16;
            float bb = bi[col];
#pragma unroll
            for (int mi = 0; mi < 4; ++mi)
#pragma unroll
                for (int r = 0; r < 4; ++r) {
                    int rowg = m0 + wm + mi * 16 + quad * 4 + r;
                    C[(size_t)rowg * E_DIM + col] =
                        (bf16)((R.a[mi][ni][r] + bb) * scale);
                }
        }
    } else if (widx == 2) {
#pragma unroll
        for (int ni = 0; ni < 4; ++ni) {
            int col = n0 + wn + ni * 16 + l16;   // h*64 + d
            float bb = bv[col];
#pragma unroll
            for (int mi = 0; mi < 4; ++mi) {
                int row0 = m0 + wm + mi * 16 + quad * 4;  // b*2048 + s
                int bidx = row0 >> 11, s = row0 & 2047;
                bf16x4 pk;
#pragma unroll
                for (int r = 0; r < 4; ++r) pk[r] = (bf16)(R.a[mi][ni][r] + bb);
                *(bf16x4*)(&vt[((size_t)(bidx * H_DIM) * 64 + col) * S_DIM + s]) = pk;
            }
        }
    } else {
#pragma unroll
        for (int ni = 0; ni < 4; ++ni) {
            int col = n0 + wn + ni * 16 + l16;
#pragma unroll
            for (int mi = 0; mi < 4; ++mi)
#pragma unroll
                for (int r = 0; r < 4; ++r) {
                    int rowg = m0 + wm + mi * 16 + quad * 4 + r;
                    lg[(size_t)rowg * M_DIM + col] = (bf16)R.a[mi][ni][r];
                }
        }
    }
}

// ---------------------------------------------------------------------------
// Output projection: 64x128 tiles, XCD-grouped 1D grid (512 blocks).
// ---------------------------------------------------------------------------
__global__ void __launch_bounds__(256, 2)
gemm_out64(const bf16* __restrict__ A, const bf16* __restrict__ Bm,
           const float* __restrict__ bias, float* __restrict__ C)
{
    __shared__ __align__(16) bf16 As[2 * 2048];   //  8 KB (64x32 dbuf)
    __shared__ __align__(16) bf16 Bs[2 * 4096];   // 16 KB (128x32 dbuf)
    const int tid  = threadIdx.x;
    const int lane = tid & 63;
    const int wave = tid >> 6;
    const int quad = lane >> 4;
    const int l16  = lane & 15;
    const int wm   = (wave >> 1) * 32;
    const int wn   = (wave & 1) * 64;
    const int lid  = blockIdx.x;
    const int xcd  = lid & 7;
    const int idx  = lid >> 3;        // 0..63
    const int mloc = idx >> 3;        // 0..7
    const int nn   = idx & 7;
    const int m0   = (mloc * 8 + xcd) * 64;
    const int n0   = nn * 128;
    const int K    = E_DIM;

    f32x4 acc[2][4];
#pragma unroll
    for (int i = 0; i < 2; ++i)
#pragma unroll
        for (int j = 0; j < 4; ++j) acc[i][j] = f32x4{0.f, 0.f, 0.f, 0.f};

    int a_s  = wave * 64 + lane;
    int a_r  = a_s >> 2;
    int a_k  = (a_s & 3) ^ ((a_r >> 1) & 3);
    int b_s0 = wave * 128 + lane;
    int b_r0 = b_s0 >> 2;
    int b_k0 = (b_s0 & 3) ^ ((b_r0 >> 1) & 3);
    int b_s1 = b_s0 + 64;
    int b_r1 = b_s1 >> 2;
    int b_k1 = (b_s1 & 3) ^ ((b_r1 >> 1) & 3);
    const bf16* gA  = A  + (size_t)(m0 + a_r) * K + a_k * 8;
    const bf16* gB0 = Bm + (size_t)(n0 + b_r0) * K + b_k0 * 8;
    const bf16* gB1 = Bm + (size_t)(n0 + b_r1) * K + b_k1 * 8;

#define STAGE64(buf, k0)                                                   \
    do {                                                                   \
        async_cp16(gA  + (k0), &As[(buf) * 2048 + wave * 512]);            \
        async_cp16(gB0 + (k0), &Bs[(buf) * 4096 + wave * 1024]);           \
        async_cp16(gB1 + (k0), &Bs[(buf) * 4096 + wave * 1024 + 512]);     \
    } while (0)

    STAGE64(0, 0);
    int buf = 0;
    for (int k0 = 0; k0 < K; k0 += 32) {
        __syncthreads();
        if (k0 + 32 < K) STAGE64(buf ^ 1, k0 + 32);
        const bf16* Ab = As + buf * 2048;
        const bf16* Bb = Bs + buf * 4096;
        bf16x8 af[2], bfr[4];
#pragma unroll
        for (int mi = 0; mi < 2; ++mi) {
            int m    = wm + mi * 16 + l16;
            int slot = quad ^ ((m >> 1) & 3);
            af[mi]   = *(const bf16x8*)(&Ab[(m * 4 + slot) * 8]);
        }
#pragma unroll
        for (int ni = 0; ni < 4; ++ni) {
            int n    = wn + ni * 16 + l16;
            int slot = quad ^ ((n >> 1) & 3);
            bfr[ni]  = *(const bf16x8*)(&Bb[(n * 4 + slot) * 8]);
        }
#pragma unroll
        for (int mi = 0; mi < 2; ++mi)
#pragma unroll
            for (int ni = 0; ni < 4; ++ni)
                acc[mi][ni] = __builtin_amdgcn_mfma_f32_16x16x32_bf16(
                    af[mi], bfr[ni], acc[mi][ni], 0, 0, 0);
        buf ^= 1;
    }
#undef STAGE64

#pragma unroll
    for (int ni = 0; ni < 4; ++ni) {
        int col  = n0 + wn + ni * 16 + l16;
        float bb = bias[col];
#pragma unroll
        for (int mi = 0; mi < 2; ++mi)
#pragma unroll
            for (int r = 0; r < 4; ++r) {
                int rowg = m0 + wm + mi * 16 + quad * 4 + r;
                C[(size_t)rowg * E_DIM + col] = acc[mi][ni][r] + bb;
            }
    }
}

// ---------------------------------------------------------------------------
// Flash attention v13 (REVERT — proven 72.0 us, total 215.1).
// 32x32x16 MFMA, fully in-register softmax/P:
//   * QK^T computes S^T (C col = q = lane&31, row = key via m74/m101 layout);
//     after 2 key-tiles each lane holds the FULL 64-key P row for its q.
//   * pi = swap key-axis bits 2<->3, applied to BOTH P and V (exact).  P
//     collapses to ap[kc][j] = exp2(sc[kc>>1][(kc&1)*8+j]) — zero cross-lane.
//   * V staged with pi folded into LDS write addresses (two b64 per 16B).
//   * reg-staged double-buffered LDS, one barrier per 64-key tile.
// v14/v15 occupancy experiments both regressed (bank conflicts / barrier
// stall) — this structure is the local optimum for the flash family.
// ---------------------------------------------------------------------------
__global__ void __launch_bounds__(256, 2)
flash_attn(const bf16* __restrict__ q, const bf16* __restrict__ k,
           const bf16* __restrict__ vt, const bf16* __restrict__ lg,
           const bf16* __restrict__ memt, bf16* __restrict__ outc)
{
    __shared__ __align__(16) bf16 Ks[2 * 4096];      // 16 KB [key][d] swz
    __shared__ __align__(16) bf16 Vs[2 * 4096];      // 16 KB [d][slot] pi+swz
    const int tid  = threadIdx.x;
    const int lane = tid & 63;
    const int wave = tid >> 6;
    const int hi   = lane >> 5;
    const int l32  = lane & 31;
    // XCD-swizzled decode: 16 q-tiles (128 rows) of one (b,h); 4 bh per XCD
    const int lid = blockIdx.x;               // 0..511
    const int xcd = lid & 7;
    const int kk  = lid >> 3;                 // 0..63
    const int qt  = kk & 15;                  // 0..15
    const int p   = ((kk >> 4) << 3) | xcd;   // 0..31
    const int b   = p >> 4;
    const int h   = p & 15;
    const int q0  = qt * 128 + wave * 32;     // this wave's first q row (32)

    const bf16* qb = q  + (size_t)(b * S_DIM + q0) * E_DIM + h * D_DIM;
    const bf16* kb = k  + (size_t)(b * S_DIM) * E_DIM + h * D_DIM;
    const bf16* vb = vt + (size_t)(b * H_DIM + h) * D_DIM * S_DIM;

    // staging geometry: slots s0,s1; row = s>>3, global chunk gc = (s&7)^(row&7)
    const int s_s0 = wave * 128 + lane;
    const int s_r0 = s_s0 >> 3;
    const int s_g0 = (s_s0 & 7) ^ (s_r0 & 7);
    const int s_s1 = s_s0 + 64;
    const int s_r1 = s_s1 >> 3;
    const int s_g1 = (s_s1 & 7) ^ (s_r1 & 7);
    const bf16* gK0 = kb + (size_t)s_r0 * E_DIM + s_g0 * 8;
    const bf16* gK1 = kb + (size_t)s_r1 * E_DIM + s_g1 * 8;
    const bf16* gV0 = vb + (size_t)s_r0 * S_DIM + s_g0 * 8;
    const bf16* gV1 = vb + (size_t)s_r1 * S_DIM + s_g1 * 8;

    // K LDS dests (linear, 16B per lane, two slots)
    const int kd0 = wave * 1024 + lane * 8;            // elements
    // V LDS dests (pi-permuted + XOR swizzle), two b64 per staged 16B
    const int v00 = s_r0 * 64 + (((s_g0 & ~1)    ) ^ (s_r0 & 7)) * 8 + (s_g0 & 1) * 4;
    const int v01 = s_r0 * 64 + (((s_g0 & ~1) | 1) ^ (s_r0 & 7)) * 8 + (s_g0 & 1) * 4;
    const int v10 = s_r1 * 64 + (((s_g1 & ~1)    ) ^ (s_r1 & 7)) * 8 + (s_g1 & 1) * 4;
    const int v11 = s_r1 * 64 + (((s_g1 & ~1) | 1) ^ (s_r1 & 7)) * 8 + (s_g1 & 1) * 4;

    // Q B-frags (persistent, pre-scaled by C1): B[k=d][col=q=l32];
    // chunk c: d = c*16 + hi*8 + j
    bf16x8 qfr[4];
#pragma unroll
    for (int c = 0; c < 4; ++c)
        qfr[c] = *(const bf16x8*)(qb + (size_t)l32 * E_DIM + c * 16 + hi * 8);

    bf16x8 vones;
#pragma unroll
    for (int j = 0; j < 8; ++j) vones[j] = (bf16)1.0f;

    f32x16 o_acc0 = zero16(), o_acc1 = zero16(), osum = zero16();

    // ---- prologue: reg-load tile 0, write to buf 0, barrier --------------
    {
        i32x4 rK0 = *(const i32x4*)(gK0);
        i32x4 rK1 = *(const i32x4*)(gK1);
        i32x4 rV0 = *(const i32x4*)(gV0);
        i32x4 rV1 = *(const i32x4*)(gV1);
        *(i32x4*)(&Ks[kd0])       = rK0;
        *(i32x4*)(&Ks[kd0 + 512]) = rK1;
        *(i32x2*)(&Vs[v00]) = i32x2{rV0[0], rV0[1]};
        *(i32x2*)(&Vs[v01]) = i32x2{rV0[2], rV0[3]};
        *(i32x2*)(&Vs[v10]) = i32x2{rV1[0], rV1[1]};
        *(i32x2*)(&Vs[v11]) = i32x2{rV1[2], rV1[3]};
    }
    __syncthreads();

    int buf = 0;
    for (int kt = 0; kt < S_DIM; kt += 64) {
        // ---- issue next tile's loads to regs (latency hides under compute)
        const bool pre = (kt + 64 < S_DIM);
        i32x4 nK0, nK1, nV0, nV1;
        if (pre) {
            const size_t ko = (size_t)(kt + 64) * E_DIM;
            nK0 = *(const i32x4*)(gK0 + ko);
            nK1 = *(const i32x4*)(gK1 + ko);
            nV0 = *(const i32x4*)(gV0 + (kt + 64));
            nV1 = *(const i32x4*)(gV1 + (kt + 64));
        }
        const bf16* Kb = Ks + buf * 4096;
        const bf16* Vb = Vs + buf * 4096;

        // ---- QK^T: S^T[key][q], two 32-key tiles, d in 4 chunks of 16 ----
        f32x16 sc0 = zero16(), sc1 = zero16();
        __builtin_amdgcn_s_setprio(1);
#pragma unroll
        for (int c = 0; c < 4; ++c) {
            const int cc  = c * 2 + hi;
            const int swz = (cc ^ (l32 & 7)) * 8;
            bf16x8 kf0 = *(const bf16x8*)(&Kb[l32 * 64 + swz]);
            bf16x8 kf1 = *(const bf16x8*)(&Kb[(32 + l32) * 64 + swz]);
            sc0 = MFMA32(kf0, qfr[c], sc0);
            sc1 = MFMA32(kf1, qfr[c], sc1);
        }
        __builtin_amdgcn_s_setprio(0);

        // ---- in-register P: ap[kc][j] = exp2(sc[kc>>1][(kc&1)*8+j]) ------
        bf16x8 ap[4];
#pragma unroll
        for (int kc = 0; kc < 4; ++kc) {
            const f32x16 sct = (kc < 2) ? sc0 : sc1;
            const int base = (kc & 1) * 8;
#pragma unroll
            for (int j = 0; j < 8; ++j)
                ap[kc][j] = (bf16)exp2f(sct[base + j]);
        }

        // ---- O += P @ V_perm ;  osum += P @ 1 ----------------------------
        __builtin_amdgcn_s_setprio(1);
#pragma unroll
        for (int kc = 0; kc < 4; ++kc) {
            const int swz = ((kc * 2 + hi) ^ (l32 & 7)) * 8;
            bf16x8 vf0 = *(const bf16x8*)(&Vb[l32 * 64 + swz]);
            bf16x8 vf1 = *(const bf16x8*)(&Vb[(32 + l32) * 64 + swz]);
            o_acc0 = MFMA32(ap[kc], vf0, o_acc0);
            o_acc1 = MFMA32(ap[kc], vf1, o_acc1);
            osum   = MFMA32(ap[kc], vones, osum);
        }
        __builtin_amdgcn_s_setprio(0);

        // ---- write-late: own loads have landed; stage into buf^1 ---------
        if (pre) {
            const int bo = (buf ^ 1) * 4096;
            *(i32x4*)(&Ks[bo + kd0])       = nK0;
            *(i32x4*)(&Ks[bo + kd0 + 512]) = nK1;
            *(i32x2*)(&Vs[bo + v00]) = i32x2{nV0[0], nV0[1]};
            *(i32x2*)(&Vs[bo + v01]) = i32x2{nV0[2], nV0[3]};
            *(i32x2*)(&Vs[bo + v10]) = i32x2{nV1[0], nV1[1]};
            *(i32x2*)(&Vs[bo + v11]) = i32x2{nV1[2], nV1[3]};
        }
        __syncthreads();
        buf ^= 1;
    }

    // rows of osum match rows of o_acc: q_local = (r&3)+8*(r>>2)+4*hi
    float linv[16];
#pragma unroll
    for (int r = 0; r < 16; ++r) linv[r] = 1.f / osum[r];

    // ---- fused memory cross-attn (32x32): ep = exp2(C1*lg),
    //      macc = ep @ (0.5*mem^T), msum = ep @ 1 --------------------------
    const bf16* Pr = lg   + (size_t)(b * S_DIM + q0) * M_DIM;
    const bf16* Mt = memt + (size_t)(h * D_DIM) * M_DIM;
    f32x16 macc0 = zero16(), macc1 = zero16(), msum = zero16();
#pragma unroll
    for (int mc = 0; mc < 16; ++mc) {
        bf16x8 raw = *(const bf16x8*)(Pr + (size_t)l32 * M_DIM + mc * 16 + hi * 8);
        bf16x8 epv;
#pragma unroll
        for (int j = 0; j < 8; ++j) epv[j] = (bf16)exp2f(C1 * (float)raw[j]);
        bf16x8 bm0 = *(const bf16x8*)(Mt + (size_t)l32 * M_DIM        + mc * 16 + hi * 8);
        bf16x8 bm1 = *(const bf16x8*)(Mt + (size_t)(32 + l32) * M_DIM + mc * 16 + hi * 8);
        macc0 = MFMA32(epv, bm0, macc0);
        macc1 = MFMA32(epv, bm1, macc1);
        msum  = MFMA32(epv, vones, msum);
    }

    // ---- epilogue: comb = attn/l + mem/msum ------------------------------
    bf16* ob = outc + (size_t)(b * S_DIM + q0) * E_DIM + h * D_DIM;
#pragma unroll
    for (int r = 0; r < 16; ++r) {
        const int qrow = (r & 3) + 8 * (r >> 2) + 4 * hi;
        const float mi = 1.f / msum[r];
        ob[(size_t)qrow * E_DIM + l32]      = (bf16)(o_acc0[r] * linv[r] + macc0[r] * mi);
        ob[(size_t)qrow * E_DIM + 32 + l32] = (bf16)(o_acc1[r] * linv[r] + macc1[r] * mi);
    }
}

// ---------------------------------------------------------------------------
extern "C" void kernel_launch(void* const* d_in, const int* in_sizes, int n_in,
                              void* d_out, int out_size, void* d_ws, size_t ws_size,
                              hipStream_t stream)
{
    (void)in_sizes; (void)n_in; (void)out_size; (void)ws_size;
    const float* x   = (const float*)d_in[0];
    const float* Wq  = (const float*)d_in[1];
    const float* bq  = (const float*)d_in[2];
    const float* Wk  = (const float*)d_in[3];
    const float* bk  = (const float*)d_in[4];
    const float* Wv  = (const float*)d_in[5];
    const float* bv  = (const float*)d_in[6];
    const float* Wo  = (const float*)d_in[7];
    const float* bo  = (const float*)d_in[8];
    const float* mem = (const float*)d_in[9];
    float* out = (float*)d_out;

    // bf16 workspace layout (elements), ~34 MB
    bf16* w = (bf16*)d_ws;
    const size_t NE = (size_t)NROW * E_DIM;            // 4 Mi
    const size_t EE = (size_t)E_DIM * E_DIM;           // 1 Mi
    bf16* xb      = w;                                 // 4M
    bf16* q_ws    = w + NE;                            // 4M (later: comb)
    bf16* k_ws    = w + 2 * NE;                        // 4M
    bf16* Wqb     = w + 3 * NE;                        // 1M
    bf16* Wkb     = Wqb + EE;
    bf16* Wvb     = Wkb + EE;
    bf16* Wob     = Wvb + EE;
    bf16* memb    = Wob + EE;                          // 0.25M
    bf16* lg_ws   = memb + (size_t)M_DIM * E_DIM;      // 1M (raw logits)
    bf16* memt_ws = lg_ws + (size_t)NROW * M_DIM;      // 0.25M
    // v^T lives inside d_out (4M bf16 in 16MB fp32 buffer), consumed by
    // flash before the final GEMM overwrites d_out.
    bf16* vt_ws = (bf16*)d_out;                        // 4M

    dim3 blk(256);

    // ---- batched fp32 -> bf16 (+ 0.5*mem^T), grid-stride ------------------
    conv_all<<<dim3(2048), blk, 0, stream>>>(
        x, Wq, Wk, Wv, Wo, mem, xb, Wqb, Wkb, Wvb, Wob, memb, memt_ws);

    // ---- fused QKV + raw memory logits (832 blocks, XCD-grouped) ----------
    gemm_qkvl<<<dim3(832), blk, 0, stream>>>(
        xb, Wqb, Wkb, Wvb, memb, bq, bk, bv, q_ws, k_ws, vt_ws, lg_ws);

    // ---- flash attention + fused memory cross-attn (512 blocks) -----------
    flash_attn<<<dim3(512), blk, 0, stream>>>(
        q_ws, k_ws, vt_ws, lg_ws, memt_ws, q_ws);

    // ---- output projection (512 blocks, XCD-grouped, fp32 out) ------------
    gemm_out64<<<dim3(512), blk, 0, stream>>>(
        q_ws, Wob, bo, out);
}